// Round 1
// baseline (2069.931 us; speedup 1.0000x reference)
//
#include <hip/hip_runtime.h>
#include <hip/hip_bf16.h>

typedef __bf16 bf16_t;
typedef bf16_t bf16x8 __attribute__((ext_vector_type(8)));
typedef float f32x4 __attribute__((ext_vector_type(4)));

#define DD 256
#define MM 64
#define RR 12

__device__ __forceinline__ float gelu_tanh(float x) {
    float x3 = x * x * x;
    return 0.5f * x * (1.0f + tanhf(0.7978845608028654f * (x + 0.044715f * x3)));
}

// ---------- weight prep: fp32 [K][C] -> bf16 transposed [C][K], batched over blockIdx.y ----------
__global__ void cvt_transpose_kernel(const float* __restrict__ src, bf16_t* __restrict__ dst,
                                     int K, int C) {
    int m = blockIdx.y;
    const float* s = src + (size_t)m * K * C;
    bf16_t* d = dst + (size_t)m * K * C;
    int idx = blockIdx.x * 256 + threadIdx.x;
    if (idx < K * C) {
        int k = idx / C, c = idx - k * C;
        d[c * K + k] = (bf16_t)s[idx];
    }
}

// ---------- embedding: x[n][d] = emb_table[z[n]] @ emb_W + emb_b ----------
__global__ void embed_kernel(const int* __restrict__ z, const float* __restrict__ table,
                             const float* __restrict__ W, const float* __restrict__ b,
                             float* __restrict__ x) {
    int n = blockIdx.x, d = threadIdx.x;
    int zi = z[n];
    const float* tr = table + zi * 5;
    float acc = b[d];
#pragma unroll
    for (int h = 0; h < 5; ++h) acc += tr[h] * W[h * DD + d];
    x[(size_t)n * DD + d] = acc;
}

// ---------- bf16 MFMA GEMM: C = [res +] [gelu](A @ W [+ bias]) ----------
// A fp32 [M][K], Wt bf16 transposed [NCOL][K]. BM=64, 4 waves, wave w owns rows w*16..w*16+15.
template <int K, int NCOL, bool BIAS, bool GELU, bool RES>
__global__ __launch_bounds__(256) void gemm_kernel(const float* __restrict__ A,
                                                   const bf16_t* __restrict__ Wt,
                                                   const float* __restrict__ bias,
                                                   const float* __restrict__ res,
                                                   float* __restrict__ C, int M) {
    __shared__ bf16_t As[64][40];  // 32 k per step, pad to 40 to spread banks
    const int t = threadIdx.x;
    const int wave = t >> 6, lane = t & 63;
    const int row0 = blockIdx.x * 64;
    constexpr int NF = NCOL / 16;
    f32x4 acc[NF];
#pragma unroll
    for (int i = 0; i < NF; ++i) acc[i] = (f32x4){0.f, 0.f, 0.f, 0.f};

    const int sr = t >> 2;   // staging row 0..63
    const int skq = t & 3;   // staging k-quad (8 floats each)
    const int frow = wave * 16 + (lane & 15);
    const int fko = (lane >> 4) * 8;

    for (int k0 = 0; k0 < K; k0 += 32) {
        __syncthreads();
        {  // stage A tile (fp32 -> bf16)
            int grow = row0 + sr;
            float4 p0 = {0.f, 0.f, 0.f, 0.f}, p1 = {0.f, 0.f, 0.f, 0.f};
            if (grow < M) {
                const float4* src = (const float4*)(A + (size_t)grow * K + k0 + skq * 8);
                p0 = src[0];
                p1 = src[1];
            }
            bf16x8 vv;
            vv[0] = (bf16_t)p0.x; vv[1] = (bf16_t)p0.y; vv[2] = (bf16_t)p0.z; vv[3] = (bf16_t)p0.w;
            vv[4] = (bf16_t)p1.x; vv[5] = (bf16_t)p1.y; vv[6] = (bf16_t)p1.z; vv[7] = (bf16_t)p1.w;
            *(bf16x8*)&As[sr][skq * 8] = vv;
        }
        __syncthreads();
        // A fragment: row = lane&15 (within wave's 16-row slab), k = 8*(lane>>4)+e
        bf16x8 afrag = *(const bf16x8*)&As[frow][fko];
#pragma unroll
        for (int nf = 0; nf < NF; ++nf) {
            bf16x8 bfrag = *(const bf16x8*)(Wt + (size_t)(nf * 16 + (lane & 15)) * K + k0 + fko);
            acc[nf] = __builtin_amdgcn_mfma_f32_16x16x32_bf16(afrag, bfrag, acc[nf], 0, 0, 0);
        }
    }
    // epilogue: C/D layout col = lane&15, row = (lane>>4)*4 + r  [verified layout]
#pragma unroll
    for (int nf = 0; nf < NF; ++nf) {
        int col = nf * 16 + (lane & 15);
#pragma unroll
        for (int r = 0; r < 4; ++r) {
            int row = row0 + wave * 16 + (lane >> 4) * 4 + r;
            if (row < M) {
                float vv = acc[nf][r];
                if (BIAS) vv += bias[col];
                if (GELU) vv = gelu_tanh(vv);
                if (RES) vv += res[(size_t)row * NCOL + col];
                C[(size_t)row * NCOL + col] = vv;
            }
        }
    }
}

// ---------- edge rbf: Bessel basis with polynomial envelope (p=5) ----------
__global__ void rbf_kernel(const int* __restrict__ ei, const float* __restrict__ pos,
                           const float* __restrict__ freqs, float* __restrict__ rbf, int E) {
    int e = blockIdx.x * 256 + threadIdx.x;
    if (e >= E) return;
    int i = ei[e], j = ei[E + e];
    float dx = pos[i * 3 + 0] - pos[j * 3 + 0];
    float dy = pos[i * 3 + 1] - pos[j * 3 + 1];
    float dz = pos[i * 3 + 2] - pos[j * 3 + 2];
    float dist = sqrtf(dx * dx + dy * dy + dz * dz + 1e-12f);
    float x = dist * 0.2f;  // dist / CUTOFF
    float x2 = x * x, x4 = x2 * x2;
    float env = 1.0f / x + x4 * (-21.0f + x * (35.0f - 15.0f * x));
    float out[12];
#pragma unroll
    for (int r = 0; r < 12; ++r) out[r] = env * sinf(freqs[r] * x);
    float4* dst = (float4*)(rbf + (size_t)e * 12);
    dst[0] = make_float4(out[0], out[1], out[2], out[3]);
    dst[1] = make_float4(out[4], out[5], out[6], out[7]);
    dst[2] = make_float4(out[8], out[9], out[10], out[11]);
}

// ---------- CSR build ----------
__global__ void count_kernel(const int* __restrict__ ei, int* __restrict__ deg, int E) {
    int e = blockIdx.x * 256 + threadIdx.x;
    if (e < E) atomicAdd(&deg[ei[e]], 1);
}

__global__ void scan_kernel(const int* __restrict__ deg, int* __restrict__ row_start, int N) {
    __shared__ int sdata[1024];
    int t = threadIdx.x;
    int base = 0;
    for (int start = 0; start < N; start += 1024) {
        int i = start + t;
        int val = (i < N) ? deg[i] : 0;
        sdata[t] = val;
        __syncthreads();
        for (int off = 1; off < 1024; off <<= 1) {
            int tv = (t >= off) ? sdata[t - off] : 0;
            __syncthreads();
            sdata[t] += tv;
            __syncthreads();
        }
        if (i < N) row_start[i] = base + sdata[t] - val;  // exclusive
        base += sdata[1023];
        __syncthreads();
    }
    if (t == 0) row_start[N] = base;
}

__global__ void fill_kernel(const int* __restrict__ ei, const int* __restrict__ row_start,
                            int* __restrict__ cursor, int* __restrict__ csr_eid,
                            int* __restrict__ csr_j, int E) {
    int e = blockIdx.x * 256 + threadIdx.x;
    if (e < E) {
        int i = ei[e];
        int p = atomicAdd(&cursor[i], 1);
        int o = row_start[i] + p;
        csr_eid[o] = e;
        csr_j[o] = ei[E + e];
    }
}

// ---------- message gather: agg[i][m] = sum_{e: dst=i} v[j_e][m] * (rbf[e] @ Wrbf)[m] ----------
__global__ __launch_bounds__(256) void msg_kernel(const int* __restrict__ row_start,
                                                  const int* __restrict__ csr_eid,
                                                  const int* __restrict__ csr_j,
                                                  const float* __restrict__ rbf,
                                                  const float* __restrict__ v,
                                                  const float* __restrict__ Wrbf,
                                                  float* __restrict__ agg, int N) {
    int wave = threadIdx.x >> 6, lane = threadIdx.x & 63;
    int nd = blockIdx.x * 4 + wave;
    if (nd >= N) return;
    float wr[12];
#pragma unroll
    for (int r = 0; r < 12; ++r) wr[r] = Wrbf[r * 64 + lane];
    int s = row_start[nd], epos = row_start[nd + 1];
    float acc = 0.f;
    for (int idx = s; idx < epos; ++idx) {
        int eid = csr_eid[idx];
        int j = csr_j[idx];
        const float* rb = rbf + (size_t)eid * 12;
        float g = 0.f;
#pragma unroll
        for (int r = 0; r < 12; ++r) g += rb[r] * wr[r];
        acc += v[(size_t)j * 64 + lane] * g;
    }
    agg[(size_t)nd * 64 + lane] = acc;
}

extern "C" void kernel_launch(void* const* d_in, const int* in_sizes, int n_in, void* d_out,
                              int out_size, void* d_ws, size_t ws_size, hipStream_t stream) {
    const int* z = (const int*)d_in[0];
    const float* pos = (const float*)d_in[1];
    const int* ei = (const int*)d_in[4];
    const float* emb_table = (const float*)d_in[5];
    const float* emb_W = (const float*)d_in[6];
    const float* emb_b = (const float*)d_in[7];
    const float* freqs = (const float*)d_in[8];
    const float* fc0_W = (const float*)d_in[9];
    const float* fc0_b = (const float*)d_in[10];
    const float* conv_Wv = (const float*)d_in[11];
    const float* conv_Wrbf = (const float*)d_in[12];
    const float* conv_Wout = (const float*)d_in[13];
    const float* fc_W = (const float*)d_in[14];
    const float* fc_b = (const float*)d_in[15];
    float* x = (float*)d_out;

    const int N = in_sizes[0];      // z is [N,1]
    const int E = in_sizes[4] / 2;  // edge_index is [2,E]

    // ---- workspace carve (all 256B-aligned) ----
    char* wsp = (char*)d_ws;
    auto alloc = [&](size_t bytes) {
        void* p = (void*)wsp;
        wsp += (bytes + 255) & ~(size_t)255;
        return p;
    };
    float* tmp = (float*)alloc((size_t)N * DD * 4);
    float* v = (float*)alloc((size_t)N * MM * 4);
    float* agg = (float*)alloc((size_t)N * MM * 4);
    float* rbf = (float*)alloc((size_t)E * RR * 4);
    int* deg = (int*)alloc((size_t)N * 4);
    int* cursor = (int*)alloc((size_t)N * 4);
    int* row_start = (int*)alloc((size_t)(N + 1) * 4);
    int* csr_eid = (int*)alloc((size_t)E * 4);
    int* csr_j = (int*)alloc((size_t)E * 4);
    bf16_t* wbf = (bf16_t*)alloc((size_t)786432 * 2);
    bf16_t* fc0t = wbf;                  // 2 x [256][256]
    bf16_t* fct = wbf + 2 * 65536;       // 8 x [256][256]
    bf16_t* wvt = wbf + 10 * 65536;      // 4 x [64][256]   (Wv transposed)
    bf16_t* wott = wvt + 4 * 16384;      // 4 x [256][64]   (Wout transposed)

    // ---- weight prep ----
    cvt_transpose_kernel<<<dim3(256, 2), 256, 0, stream>>>(fc0_W, fc0t, 256, 256);
    cvt_transpose_kernel<<<dim3(256, 8), 256, 0, stream>>>(fc_W, fct, 256, 256);
    cvt_transpose_kernel<<<dim3(64, 4), 256, 0, stream>>>(conv_Wv, wvt, 256, 64);
    cvt_transpose_kernel<<<dim3(64, 4), 256, 0, stream>>>(conv_Wout, wott, 64, 256);

    // ---- node init: embedding + fc0 (2 gelu layers) ----
    embed_kernel<<<N, 256, 0, stream>>>(z, emb_table, emb_W, emb_b, x);
    int gm = (N + 63) / 64;
    gemm_kernel<256, 256, true, true, false><<<gm, 256, 0, stream>>>(x, fc0t, fc0_b, nullptr, tmp, N);
    gemm_kernel<256, 256, true, true, false><<<gm, 256, 0, stream>>>(tmp, fc0t + 65536, fc0_b + 256, nullptr, x, N);

    // ---- edge rbf ----
    rbf_kernel<<<(E + 255) / 256, 256, 0, stream>>>(ei, pos, freqs, rbf, E);

    // ---- CSR by destination ----
    hipMemsetAsync(deg, 0, (size_t)N * 4, stream);
    hipMemsetAsync(cursor, 0, (size_t)N * 4, stream);
    count_kernel<<<(E + 255) / 256, 256, 0, stream>>>(ei, deg, E);
    scan_kernel<<<1, 1024, 0, stream>>>(deg, row_start, N);
    fill_kernel<<<(E + 255) / 256, 256, 0, stream>>>(ei, row_start, cursor, csr_eid, csr_j, E);

    // ---- interaction blocks ----
    for (int n = 0; n < 4; ++n) {
        gemm_kernel<256, 64, false, false, false>
            <<<gm, 256, 0, stream>>>(x, wvt + n * 16384, nullptr, nullptr, v, N);
        msg_kernel<<<(N + 3) / 4, 256, 0, stream>>>(row_start, csr_eid, csr_j, rbf, v,
                                                    conv_Wrbf + n * RR * MM, agg, N);
        gemm_kernel<64, 256, false, false, true>
            <<<gm, 256, 0, stream>>>(agg, wott + n * 16384, nullptr, x, x, N);
        gemm_kernel<256, 256, true, true, false>
            <<<gm, 256, 0, stream>>>(x, fct + (n * 2) * 65536, fc_b + n * 2 * 256, nullptr, tmp, N);
        gemm_kernel<256, 256, true, true, true>
            <<<gm, 256, 0, stream>>>(tmp, fct + (n * 2 + 1) * 65536, fc_b + (n * 2 + 1) * 256, x, x, N);
    }
}

// Round 2
// 1617.363 us; speedup vs baseline: 1.2798x; 1.2798x over previous
//
#include <hip/hip_runtime.h>
#include <hip/hip_bf16.h>

typedef __bf16 bf16_t;
typedef bf16_t bf16x8 __attribute__((ext_vector_type(8)));
typedef float f32x4 __attribute__((ext_vector_type(4)));

#define DD 256
#define MM 64
#define RR 12

__device__ __forceinline__ float gelu_tanh(float x) {
    float x3 = x * x * x;
    return 0.5f * x * (1.0f + tanhf(0.7978845608028654f * (x + 0.044715f * x3)));
}

__device__ __forceinline__ bf16x8 zero8() {
    bf16x8 z;
#pragma unroll
    for (int i = 0; i < 8; ++i) z[i] = (bf16_t)0.f;
    return z;
}

// ---------- weight prep: fp32 [K][C] -> bf16 transposed [C][K], batched over blockIdx.y ----------
__global__ void cvt_transpose_kernel(const float* __restrict__ src, bf16_t* __restrict__ dst,
                                     int K, int C) {
    int m = blockIdx.y;
    const float* s = src + (size_t)m * K * C;
    bf16_t* d = dst + (size_t)m * K * C;
    int idx = blockIdx.x * 256 + threadIdx.x;
    if (idx < K * C) {
        int k = idx / C, c = idx - k * C;
        d[c * K + k] = (bf16_t)s[idx];
    }
}

// ---------- embedding: xb[n][d] = bf16(emb_table[z[n]] @ emb_W + emb_b) ----------
__global__ void embed_kernel(const int* __restrict__ z, const float* __restrict__ table,
                             const float* __restrict__ W, const float* __restrict__ b,
                             bf16_t* __restrict__ xb) {
    int n = blockIdx.x, d = threadIdx.x;
    int zi = z[n];
    const float* tr = table + zi * 5;
    float acc = b[d];
#pragma unroll
    for (int h = 0; h < 5; ++h) acc += tr[h] * W[h * DD + d];
    xb[(size_t)n * DD + d] = (bf16_t)acc;
}

// ---------- register-B MFMA GEMM ----------
// A bf16 [M][K], Wt bf16 transposed [NCOL][K]. 4 waves; block tile = 32 rows x NCOL cols;
// wave owns NCOL/4 cols. B fully preloaded into VGPRs; persistent blocks loop over row tiles.
template <int K, int NCOL, bool BIAS, bool GELU, bool RES, bool WF32, bool WBF16>
__global__ __launch_bounds__(256, 2) void gemm_rb(const bf16_t* __restrict__ A,
                                                  const bf16_t* __restrict__ Wt,
                                                  const float* __restrict__ bias,
                                                  const float* __restrict__ res,
                                                  float* __restrict__ Cf,
                                                  bf16_t* __restrict__ Cb, int M) {
    constexpr int NSTEP = K / 32;
    constexpr int NF = NCOL / 64;  // 16-col fragments per wave
    const int t = threadIdx.x;
    const int wave = t >> 6, lane = t & 63;
    const int l15 = lane & 15, lhi = lane >> 4;
    const int colbase = wave * (NCOL / 4);

    // preload B into registers (shared by all row tiles)
    bf16x8 bfr[NSTEP][NF];
#pragma unroll
    for (int ks = 0; ks < NSTEP; ++ks)
#pragma unroll
        for (int nf = 0; nf < NF; ++nf)
            bfr[ks][nf] =
                *(const bf16x8*)(Wt + (size_t)(colbase + nf * 16 + l15) * K + ks * 32 + lhi * 8);

    const bf16x8 z8 = zero8();
    for (int row0 = blockIdx.x * 32; row0 < M; row0 += gridDim.x * 32) {
        const int r0 = row0 + l15, r1 = row0 + 16 + l15;
        const bool g0 = r0 < M, g1 = r1 < M;
        const bf16_t* a0p = A + (size_t)r0 * K + lhi * 8;
        const bf16_t* a1p = A + (size_t)r1 * K + lhi * 8;

        f32x4 acc[2][NF];
#pragma unroll
        for (int mf = 0; mf < 2; ++mf)
#pragma unroll
            for (int nf = 0; nf < NF; ++nf) acc[mf][nf] = (f32x4){0.f, 0.f, 0.f, 0.f};

        bf16x8 a0 = g0 ? *(const bf16x8*)a0p : z8;
        bf16x8 a1 = g1 ? *(const bf16x8*)a1p : z8;
#pragma unroll
        for (int ks = 0; ks < NSTEP; ++ks) {
            bf16x8 n0 = z8, n1 = z8;
            if (ks + 1 < NSTEP) {
                n0 = g0 ? *(const bf16x8*)(a0p + (ks + 1) * 32) : z8;
                n1 = g1 ? *(const bf16x8*)(a1p + (ks + 1) * 32) : z8;
            }
#pragma unroll
            for (int nf = 0; nf < NF; ++nf)
                acc[0][nf] = __builtin_amdgcn_mfma_f32_16x16x32_bf16(a0, bfr[ks][nf], acc[0][nf], 0, 0, 0);
#pragma unroll
            for (int nf = 0; nf < NF; ++nf)
                acc[1][nf] = __builtin_amdgcn_mfma_f32_16x16x32_bf16(a1, bfr[ks][nf], acc[1][nf], 0, 0, 0);
            a0 = n0;
            a1 = n1;
        }

        // epilogue: C/D layout col = lane&15, row = (lane>>4)*4 + r
#pragma unroll
        for (int mf = 0; mf < 2; ++mf)
#pragma unroll
            for (int nf = 0; nf < NF; ++nf) {
                int col = colbase + nf * 16 + l15;
#pragma unroll
                for (int r = 0; r < 4; ++r) {
                    int row = row0 + mf * 16 + lhi * 4 + r;
                    if (row < M) {
                        float vv = acc[mf][nf][r];
                        if (BIAS) vv += bias[col];
                        if (GELU) vv = gelu_tanh(vv);
                        if (RES) vv += res[(size_t)row * NCOL + col];
                        if (WF32) Cf[(size_t)row * NCOL + col] = vv;
                        if (WBF16) Cb[(size_t)row * NCOL + col] = (bf16_t)vv;
                    }
                }
            }
    }
}

// ---------- edge rbf: Bessel basis with polynomial envelope (p=5) ----------
__global__ void rbf_kernel(const int* __restrict__ ei, const float* __restrict__ pos,
                           const float* __restrict__ freqs, float* __restrict__ rbf, int E) {
    int e = blockIdx.x * 256 + threadIdx.x;
    if (e >= E) return;
    int i = ei[e], j = ei[E + e];
    float dx = pos[i * 3 + 0] - pos[j * 3 + 0];
    float dy = pos[i * 3 + 1] - pos[j * 3 + 1];
    float dz = pos[i * 3 + 2] - pos[j * 3 + 2];
    float dist = sqrtf(dx * dx + dy * dy + dz * dz + 1e-12f);
    float x = dist * 0.2f;  // dist / CUTOFF
    float x2 = x * x, x4 = x2 * x2;
    float env = 1.0f / x + x4 * (-21.0f + x * (35.0f - 15.0f * x));
    float out[12];
#pragma unroll
    for (int r = 0; r < 12; ++r) out[r] = env * sinf(freqs[r] * x);
    float4* dst = (float4*)(rbf + (size_t)e * 12);
    dst[0] = make_float4(out[0], out[1], out[2], out[3]);
    dst[1] = make_float4(out[4], out[5], out[6], out[7]);
    dst[2] = make_float4(out[8], out[9], out[10], out[11]);
}

// ---------- CSR build ----------
__global__ void count_kernel(const int* __restrict__ ei, int* __restrict__ deg, int E) {
    int e = blockIdx.x * 256 + threadIdx.x;
    if (e < E) atomicAdd(&deg[ei[e]], 1);
}

__global__ void scan_kernel(const int* __restrict__ deg, int* __restrict__ row_start, int N) {
    __shared__ int sdata[1024];
    int t = threadIdx.x;
    int base = 0;
    for (int start = 0; start < N; start += 1024) {
        int i = start + t;
        int val = (i < N) ? deg[i] : 0;
        sdata[t] = val;
        __syncthreads();
        for (int off = 1; off < 1024; off <<= 1) {
            int tv = (t >= off) ? sdata[t - off] : 0;
            __syncthreads();
            sdata[t] += tv;
            __syncthreads();
        }
        if (i < N) row_start[i] = base + sdata[t] - val;  // exclusive
        base += sdata[1023];
        __syncthreads();
    }
    if (t == 0) row_start[N] = base;
}

__global__ void fill_kernel(const int* __restrict__ ei, const int* __restrict__ row_start,
                            int* __restrict__ cursor, int* __restrict__ csr_eid,
                            int* __restrict__ csr_j, int E) {
    int e = blockIdx.x * 256 + threadIdx.x;
    if (e < E) {
        int i = ei[e];
        int p = atomicAdd(&cursor[i], 1);
        int o = row_start[i] + p;
        csr_eid[o] = e;
        csr_j[o] = ei[E + e];
    }
}

// ---------- message gather: agg[i][m] = sum_{e: dst=i} v[j_e][m] * (rbf[e] @ Wrbf)[m] ----------
__global__ __launch_bounds__(256) void msg_kernel(const int* __restrict__ row_start,
                                                  const int* __restrict__ csr_eid,
                                                  const int* __restrict__ csr_j,
                                                  const float* __restrict__ rbf,
                                                  const float* __restrict__ v,
                                                  const float* __restrict__ Wrbf,
                                                  bf16_t* __restrict__ agg, int N) {
    int wave = threadIdx.x >> 6, lane = threadIdx.x & 63;
    int nd = blockIdx.x * 4 + wave;
    if (nd >= N) return;
    float wr[12];
#pragma unroll
    for (int r = 0; r < 12; ++r) wr[r] = Wrbf[r * 64 + lane];
    int s = row_start[nd], epos = row_start[nd + 1];
    float acc = 0.f;
    for (int idx = s; idx < epos; ++idx) {
        int eid = csr_eid[idx];
        int j = csr_j[idx];
        const float* rb = rbf + (size_t)eid * 12;
        float g = 0.f;
#pragma unroll
        for (int r = 0; r < 12; ++r) g += rb[r] * wr[r];
        acc += v[(size_t)j * 64 + lane] * g;
    }
    agg[(size_t)nd * 64 + lane] = (bf16_t)acc;
}

extern "C" void kernel_launch(void* const* d_in, const int* in_sizes, int n_in, void* d_out,
                              int out_size, void* d_ws, size_t ws_size, hipStream_t stream) {
    const int* z = (const int*)d_in[0];
    const float* pos = (const float*)d_in[1];
    const int* ei = (const int*)d_in[4];
    const float* emb_table = (const float*)d_in[5];
    const float* emb_W = (const float*)d_in[6];
    const float* emb_b = (const float*)d_in[7];
    const float* freqs = (const float*)d_in[8];
    const float* fc0_W = (const float*)d_in[9];
    const float* fc0_b = (const float*)d_in[10];
    const float* conv_Wv = (const float*)d_in[11];
    const float* conv_Wrbf = (const float*)d_in[12];
    const float* conv_Wout = (const float*)d_in[13];
    const float* fc_W = (const float*)d_in[14];
    const float* fc_b = (const float*)d_in[15];
    float* x = (float*)d_out;

    const int N = in_sizes[0];      // z is [N,1]
    const int E = in_sizes[4] / 2;  // edge_index is [2,E]

    // ---- workspace carve (all 256B-aligned) ----
    char* wsp = (char*)d_ws;
    auto alloc = [&](size_t bytes) {
        void* p = (void*)wsp;
        wsp += (bytes + 255) & ~(size_t)255;
        return p;
    };
    bf16_t* xb = (bf16_t*)alloc((size_t)N * DD * 2);    // bf16 mirror of x
    bf16_t* tmpb = (bf16_t*)alloc((size_t)N * DD * 2);  // fc hidden (bf16 only)
    float* v = (float*)alloc((size_t)N * MM * 4);
    bf16_t* aggb = (bf16_t*)alloc((size_t)N * MM * 2);
    float* rbf = (float*)alloc((size_t)E * RR * 4);
    int* deg = (int*)alloc((size_t)N * 4);
    int* cursor = (int*)alloc((size_t)N * 4);
    int* row_start = (int*)alloc((size_t)(N + 1) * 4);
    int* csr_eid = (int*)alloc((size_t)E * 4);
    int* csr_j = (int*)alloc((size_t)E * 4);
    bf16_t* wbf = (bf16_t*)alloc((size_t)786432 * 2);
    bf16_t* fc0t = wbf;             // 2 x [256][256]
    bf16_t* fct = wbf + 2 * 65536;  // 8 x [256][256]
    bf16_t* wvt = wbf + 10 * 65536; // 4 x [64][256]   (Wv transposed)
    bf16_t* wott = wvt + 4 * 16384; // 4 x [256][64]   (Wout transposed)

    // ---- weight prep ----
    cvt_transpose_kernel<<<dim3(256, 2), 256, 0, stream>>>(fc0_W, fc0t, 256, 256);
    cvt_transpose_kernel<<<dim3(256, 8), 256, 0, stream>>>(fc_W, fct, 256, 256);
    cvt_transpose_kernel<<<dim3(64, 4), 256, 0, stream>>>(conv_Wv, wvt, 256, 64);
    cvt_transpose_kernel<<<dim3(64, 4), 256, 0, stream>>>(conv_Wout, wott, 64, 256);

    // ---- edge rbf + CSR (independent of node path) ----
    rbf_kernel<<<(E + 255) / 256, 256, 0, stream>>>(ei, pos, freqs, rbf, E);
    hipMemsetAsync(deg, 0, (size_t)N * 4, stream);
    hipMemsetAsync(cursor, 0, (size_t)N * 4, stream);
    count_kernel<<<(E + 255) / 256, 256, 0, stream>>>(ei, deg, E);
    scan_kernel<<<1, 1024, 0, stream>>>(deg, row_start, N);
    fill_kernel<<<(E + 255) / 256, 256, 0, stream>>>(ei, row_start, cursor, csr_eid, csr_j, E);

    // ---- node init: embedding + fc0 (2 gelu layers) ----
    embed_kernel<<<N, 256, 0, stream>>>(z, emb_table, emb_W, emb_b, xb);
    const int G = 512;  // persistent blocks: 2 per CU
    gemm_rb<256, 256, true, true, false, false, true>
        <<<G, 256, 0, stream>>>(xb, fc0t, fc0_b, nullptr, nullptr, tmpb, N);
    gemm_rb<256, 256, true, true, false, true, true>
        <<<G, 256, 0, stream>>>(tmpb, fc0t + 65536, fc0_b + 256, nullptr, x, xb, N);

    // ---- interaction blocks ----
    for (int n = 0; n < 4; ++n) {
        gemm_rb<256, 64, false, false, false, true, false>
            <<<G, 256, 0, stream>>>(xb, wvt + n * 16384, nullptr, nullptr, v, nullptr, N);
        msg_kernel<<<(N + 3) / 4, 256, 0, stream>>>(row_start, csr_eid, csr_j, rbf, v,
                                                    conv_Wrbf + n * RR * MM, aggb, N);
        gemm_rb<64, 256, false, false, true, true, true>
            <<<G, 256, 0, stream>>>(aggb, wott + n * 16384, nullptr, x, x, xb, N);
        gemm_rb<256, 256, true, true, false, false, true>
            <<<G, 256, 0, stream>>>(xb, fct + (n * 2) * 65536, fc_b + n * 2 * 256, nullptr, nullptr,
                                    tmpb, N);
        gemm_rb<256, 256, true, true, true, true, true>
            <<<G, 256, 0, stream>>>(tmpb, fct + (n * 2 + 1) * 65536, fc_b + (n * 2 + 1) * 256, x, x,
                                    xb, N);
    }
}

// Round 3
// 1421.957 us; speedup vs baseline: 1.4557x; 1.1374x over previous
//
#include <hip/hip_runtime.h>
#include <hip/hip_bf16.h>

typedef __bf16 bf16_t;
typedef bf16_t bf16x8 __attribute__((ext_vector_type(8)));
typedef bf16_t bf16x4 __attribute__((ext_vector_type(4)));
typedef float f32x4 __attribute__((ext_vector_type(4)));

#define DD 256
#define MM 64
#define RR 12

__device__ __forceinline__ float gelu_tanh(float x) {
    float x3 = x * x * x;
    return 0.5f * x * (1.0f + tanhf(0.7978845608028654f * (x + 0.044715f * x3)));
}

__device__ __forceinline__ bf16x8 zero8() {
    bf16x8 z;
#pragma unroll
    for (int i = 0; i < 8; ++i) z[i] = (bf16_t)0.f;
    return z;
}

// ---------- weight prep: fp32 [K][C] -> bf16 transposed [C][K], batched over blockIdx.y ----------
__global__ void cvt_transpose_kernel(const float* __restrict__ src, bf16_t* __restrict__ dst,
                                     int K, int C) {
    int m = blockIdx.y;
    const float* s = src + (size_t)m * K * C;
    bf16_t* d = dst + (size_t)m * K * C;
    int idx = blockIdx.x * 256 + threadIdx.x;
    if (idx < K * C) {
        int k = idx / C, c = idx - k * C;
        d[c * K + k] = (bf16_t)s[idx];
    }
}

// ---------- embedding: xb[n][d] = bf16(emb_table[z[n]] @ emb_W + emb_b) ----------
__global__ void embed_kernel(const int* __restrict__ z, const float* __restrict__ table,
                             const float* __restrict__ W, const float* __restrict__ b,
                             bf16_t* __restrict__ xb) {
    int n = blockIdx.x, d = threadIdx.x;
    int zi = z[n];
    const float* tr = table + zi * 5;
    float acc = b[d];
#pragma unroll
    for (int h = 0; h < 5; ++h) acc += tr[h] * W[h * DD + d];
    xb[(size_t)n * DD + d] = (bf16_t)acc;
}

// ---------- register-B MFMA GEMM ----------
// A bf16 [M][K], Wt bf16 transposed [NCOL][K]. 4 waves; block tile = 32 rows x NCOL cols;
// wave owns NCOL/4 cols. B fully preloaded into VGPRs; persistent blocks loop over row tiles.
template <int K, int NCOL, bool BIAS, bool GELU, bool RES, bool WF32, bool WBF16>
__global__ __launch_bounds__(256, 2) void gemm_rb(const bf16_t* __restrict__ A,
                                                  const bf16_t* __restrict__ Wt,
                                                  const float* __restrict__ bias,
                                                  const float* __restrict__ res,
                                                  float* __restrict__ Cf,
                                                  bf16_t* __restrict__ Cb, int M) {
    constexpr int NSTEP = K / 32;
    constexpr int NF = NCOL / 64;  // 16-col fragments per wave
    const int t = threadIdx.x;
    const int wave = t >> 6, lane = t & 63;
    const int l15 = lane & 15, lhi = lane >> 4;
    const int colbase = wave * (NCOL / 4);

    // preload B into registers (shared by all row tiles)
    bf16x8 bfr[NSTEP][NF];
#pragma unroll
    for (int ks = 0; ks < NSTEP; ++ks)
#pragma unroll
        for (int nf = 0; nf < NF; ++nf)
            bfr[ks][nf] =
                *(const bf16x8*)(Wt + (size_t)(colbase + nf * 16 + l15) * K + ks * 32 + lhi * 8);

    const bf16x8 z8 = zero8();
    for (int row0 = blockIdx.x * 32; row0 < M; row0 += gridDim.x * 32) {
        const int r0 = row0 + l15, r1 = row0 + 16 + l15;
        const bool g0 = r0 < M, g1 = r1 < M;
        const bf16_t* a0p = A + (size_t)r0 * K + lhi * 8;
        const bf16_t* a1p = A + (size_t)r1 * K + lhi * 8;

        f32x4 acc[2][NF];
#pragma unroll
        for (int mf = 0; mf < 2; ++mf)
#pragma unroll
            for (int nf = 0; nf < NF; ++nf) acc[mf][nf] = (f32x4){0.f, 0.f, 0.f, 0.f};

        bf16x8 a0 = g0 ? *(const bf16x8*)a0p : z8;
        bf16x8 a1 = g1 ? *(const bf16x8*)a1p : z8;
#pragma unroll
        for (int ks = 0; ks < NSTEP; ++ks) {
            bf16x8 n0 = z8, n1 = z8;
            if (ks + 1 < NSTEP) {
                n0 = g0 ? *(const bf16x8*)(a0p + (ks + 1) * 32) : z8;
                n1 = g1 ? *(const bf16x8*)(a1p + (ks + 1) * 32) : z8;
            }
#pragma unroll
            for (int nf = 0; nf < NF; ++nf)
                acc[0][nf] = __builtin_amdgcn_mfma_f32_16x16x32_bf16(a0, bfr[ks][nf], acc[0][nf], 0, 0, 0);
#pragma unroll
            for (int nf = 0; nf < NF; ++nf)
                acc[1][nf] = __builtin_amdgcn_mfma_f32_16x16x32_bf16(a1, bfr[ks][nf], acc[1][nf], 0, 0, 0);
            a0 = n0;
            a1 = n1;
        }

        // epilogue: C/D layout col = lane&15, row = (lane>>4)*4 + r
#pragma unroll
        for (int mf = 0; mf < 2; ++mf)
#pragma unroll
            for (int nf = 0; nf < NF; ++nf) {
                int col = colbase + nf * 16 + l15;
#pragma unroll
                for (int r = 0; r < 4; ++r) {
                    int row = row0 + mf * 16 + lhi * 4 + r;
                    if (row < M) {
                        float vv = acc[mf][nf][r];
                        if (BIAS) vv += bias[col];
                        if (GELU) vv = gelu_tanh(vv);
                        if (RES) vv += res[(size_t)row * NCOL + col];
                        if (WF32) Cf[(size_t)row * NCOL + col] = vv;
                        if (WBF16) Cb[(size_t)row * NCOL + col] = (bf16_t)vv;
                    }
                }
            }
    }
}

// ---------- CSR build ----------
__global__ void count_kernel(const int* __restrict__ ei, int* __restrict__ deg, int E) {
    int e = blockIdx.x * 256 + threadIdx.x;
    if (e < E) atomicAdd(&deg[ei[e]], 1);
}

// hierarchical scan: local 1024-scan -> scan of block sums -> add offsets
__global__ void scan_local(const int* __restrict__ deg, int* __restrict__ rs,
                           int* __restrict__ bsum, int N) {
    __shared__ int sd[1024];
    int t = threadIdx.x, i = blockIdx.x * 1024 + t;
    int val = (i < N) ? deg[i] : 0;
    sd[t] = val;
    __syncthreads();
    for (int off = 1; off < 1024; off <<= 1) {
        int tv = (t >= off) ? sd[t - off] : 0;
        __syncthreads();
        sd[t] += tv;
        __syncthreads();
    }
    if (i < N) rs[i] = sd[t] - val;  // local exclusive
    if (t == 1023) bsum[blockIdx.x] = sd[1023];
}

__global__ void scan_bsums(int* __restrict__ bsum, int nb) {
    if (threadIdx.x == 0) {
        int run = 0;
        for (int b = 0; b < nb; ++b) {
            int v = bsum[b];
            bsum[b] = run;
            run += v;
        }
        bsum[nb] = run;
    }
}

__global__ void scan_add(int* __restrict__ rs, const int* __restrict__ bsum, int N) {
    int i = blockIdx.x * 1024 + threadIdx.x;
    if (i < N) rs[i] += bsum[blockIdx.x];
    if (i == 0) rs[N] = bsum[gridDim.x];
}

__global__ void fill_kernel(const int* __restrict__ ei, const int* __restrict__ row_start,
                            int* __restrict__ cursor, int* __restrict__ csr_eid,
                            int* __restrict__ csr_j, int E) {
    int e = blockIdx.x * 256 + threadIdx.x;
    if (e < E) {
        int i = ei[e];
        int p = atomicAdd(&cursor[i], 1);
        int o = row_start[i] + p;
        csr_eid[o] = e;
        csr_j[o] = ei[E + e];
    }
}

// ---------- rbf directly in CSR order (bf16, rows padded to 16 elems / 32B) ----------
__global__ void rbf_csr_kernel(const int* __restrict__ csr_eid, const int* __restrict__ ei,
                               const float* __restrict__ pos, const float* __restrict__ freqs,
                               bf16_t* __restrict__ rbf_csr, int E) {
    int idx = blockIdx.x * 256 + threadIdx.x;
    if (idx >= E) return;
    int e = csr_eid[idx];
    int i = ei[e], j = ei[E + e];
    float dx = pos[i * 3 + 0] - pos[j * 3 + 0];
    float dy = pos[i * 3 + 1] - pos[j * 3 + 1];
    float dz = pos[i * 3 + 2] - pos[j * 3 + 2];
    float dist = sqrtf(dx * dx + dy * dy + dz * dz + 1e-12f);
    float x = dist * 0.2f;  // dist / CUTOFF
    float x4 = (x * x) * (x * x);
    float env = 1.0f / x + x4 * (-21.0f + x * (35.0f - 15.0f * x));
    bf16x8 lo;
    bf16x4 hi;
#pragma unroll
    for (int r = 0; r < 8; ++r) lo[r] = (bf16_t)(env * sinf(freqs[r] * x));
#pragma unroll
    for (int r = 0; r < 4; ++r) hi[r] = (bf16_t)(env * sinf(freqs[8 + r] * x));
    bf16_t* dst = rbf_csr + (size_t)idx * 16;
    *(bf16x8*)dst = lo;
    *(bf16x4*)(dst + 8) = hi;
}

// ---------- message gather ----------
__device__ __forceinline__ float gdot(const bf16_t* __restrict__ rb, const float* __restrict__ wr) {
    bf16x8 a = *(const bf16x8*)rb;
    bf16x4 b = *(const bf16x4*)(rb + 8);
    float g = 0.f;
#pragma unroll
    for (int r = 0; r < 8; ++r) g += (float)a[r] * wr[r];
#pragma unroll
    for (int r = 0; r < 4; ++r) g += (float)b[r] * wr[8 + r];
    return g;
}

__global__ __launch_bounds__(256) void msg_kernel(const int* __restrict__ row_start,
                                                  const int* __restrict__ csr_j,
                                                  const bf16_t* __restrict__ rbf_csr,
                                                  const bf16_t* __restrict__ v,
                                                  const float* __restrict__ Wrbf,
                                                  bf16_t* __restrict__ agg, int N) {
    int wave = threadIdx.x >> 6, lane = threadIdx.x & 63;
    int nd = blockIdx.x * 4 + wave;
    if (nd >= N) return;
    float wr[12];
#pragma unroll
    for (int r = 0; r < 12; ++r) wr[r] = Wrbf[r * 64 + lane];
    int s = row_start[nd], e = row_start[nd + 1];
    float acc = 0.f;
    int idx = s;
    for (; idx + 4 <= e; idx += 4) {
        float vv[4], gg[4];
#pragma unroll
        for (int u = 0; u < 4; ++u) {
            int j = csr_j[idx + u];
            vv[u] = (float)v[(size_t)j * 64 + lane];
            gg[u] = gdot(rbf_csr + (size_t)(idx + u) * 16, wr);
        }
#pragma unroll
        for (int u = 0; u < 4; ++u) acc += vv[u] * gg[u];
    }
    for (; idx < e; ++idx) {
        int j = csr_j[idx];
        acc += (float)v[(size_t)j * 64 + lane] * gdot(rbf_csr + (size_t)idx * 16, wr);
    }
    agg[(size_t)nd * 64 + lane] = (bf16_t)acc;
}

extern "C" void kernel_launch(void* const* d_in, const int* in_sizes, int n_in, void* d_out,
                              int out_size, void* d_ws, size_t ws_size, hipStream_t stream) {
    const int* z = (const int*)d_in[0];
    const float* pos = (const float*)d_in[1];
    const int* ei = (const int*)d_in[4];
    const float* emb_table = (const float*)d_in[5];
    const float* emb_W = (const float*)d_in[6];
    const float* emb_b = (const float*)d_in[7];
    const float* freqs = (const float*)d_in[8];
    const float* fc0_W = (const float*)d_in[9];
    const float* fc0_b = (const float*)d_in[10];
    const float* conv_Wv = (const float*)d_in[11];
    const float* conv_Wrbf = (const float*)d_in[12];
    const float* conv_Wout = (const float*)d_in[13];
    const float* fc_W = (const float*)d_in[14];
    const float* fc_b = (const float*)d_in[15];
    float* x = (float*)d_out;

    const int N = in_sizes[0];      // z is [N,1]
    const int E = in_sizes[4] / 2;  // edge_index is [2,E]

    // ---- workspace carve (all 256B-aligned) ----
    char* wsp = (char*)d_ws;
    auto alloc = [&](size_t bytes) {
        void* p = (void*)wsp;
        wsp += (bytes + 255) & ~(size_t)255;
        return p;
    };
    bf16_t* xb = (bf16_t*)alloc((size_t)N * DD * 2);    // bf16 mirror of x
    bf16_t* tmpb = (bf16_t*)alloc((size_t)N * DD * 2);  // fc hidden (bf16 only)
    bf16_t* vb = (bf16_t*)alloc((size_t)N * MM * 2);
    bf16_t* aggb = (bf16_t*)alloc((size_t)N * MM * 2);
    bf16_t* rbf_csr = (bf16_t*)alloc((size_t)E * 16 * 2);
    int* deg = (int*)alloc((size_t)N * 4);
    int* cursor = (int*)alloc((size_t)N * 4);
    int* row_start = (int*)alloc((size_t)(N + 1) * 4);
    int* bsum = (int*)alloc((size_t)256 * 4);
    int* csr_eid = (int*)alloc((size_t)E * 4);
    int* csr_j = (int*)alloc((size_t)E * 4);
    bf16_t* wbf = (bf16_t*)alloc((size_t)786432 * 2);
    bf16_t* fc0t = wbf;             // 2 x [256][256]
    bf16_t* fct = wbf + 2 * 65536;  // 8 x [256][256]
    bf16_t* wvt = wbf + 10 * 65536; // 4 x [64][256]   (Wv transposed)
    bf16_t* wott = wvt + 4 * 16384; // 4 x [256][64]   (Wout transposed)

    // ---- weight prep ----
    cvt_transpose_kernel<<<dim3(256, 2), 256, 0, stream>>>(fc0_W, fc0t, 256, 256);
    cvt_transpose_kernel<<<dim3(256, 8), 256, 0, stream>>>(fc_W, fct, 256, 256);
    cvt_transpose_kernel<<<dim3(64, 4), 256, 0, stream>>>(conv_Wv, wvt, 256, 64);
    cvt_transpose_kernel<<<dim3(64, 4), 256, 0, stream>>>(conv_Wout, wott, 64, 256);

    // ---- CSR by destination, then rbf in CSR order ----
    hipMemsetAsync(deg, 0, (size_t)N * 4, stream);
    hipMemsetAsync(cursor, 0, (size_t)N * 4, stream);
    count_kernel<<<(E + 255) / 256, 256, 0, stream>>>(ei, deg, E);
    const int nb = (N + 1023) / 1024;
    scan_local<<<nb, 1024, 0, stream>>>(deg, row_start, bsum, N);
    scan_bsums<<<1, 64, 0, stream>>>(bsum, nb);
    scan_add<<<nb, 1024, 0, stream>>>(row_start, bsum, N);
    fill_kernel<<<(E + 255) / 256, 256, 0, stream>>>(ei, row_start, cursor, csr_eid, csr_j, E);
    rbf_csr_kernel<<<(E + 255) / 256, 256, 0, stream>>>(csr_eid, ei, pos, freqs, rbf_csr, E);

    // ---- node init: embedding + fc0 (2 gelu layers) ----
    embed_kernel<<<N, 256, 0, stream>>>(z, emb_table, emb_W, emb_b, xb);
    const int G = 512;  // persistent blocks: 2 per CU
    gemm_rb<256, 256, true, true, false, false, true>
        <<<G, 256, 0, stream>>>(xb, fc0t, fc0_b, nullptr, nullptr, tmpb, N);
    gemm_rb<256, 256, true, true, false, true, true>
        <<<G, 256, 0, stream>>>(tmpb, fc0t + 65536, fc0_b + 256, nullptr, x, xb, N);

    // ---- interaction blocks ----
    for (int n = 0; n < 4; ++n) {
        gemm_rb<256, 64, false, false, false, false, true>
            <<<G, 256, 0, stream>>>(xb, wvt + n * 16384, nullptr, nullptr, nullptr, vb, N);
        msg_kernel<<<(N + 3) / 4, 256, 0, stream>>>(row_start, csr_j, rbf_csr, vb,
                                                    conv_Wrbf + n * RR * MM, aggb, N);
        gemm_rb<64, 256, false, false, true, true, true>
            <<<G, 256, 0, stream>>>(aggb, wott + n * 16384, nullptr, x, x, xb, N);
        gemm_rb<256, 256, true, true, false, false, true>
            <<<G, 256, 0, stream>>>(xb, fct + (n * 2) * 65536, fc_b + n * 2 * 256, nullptr, nullptr,
                                    tmpb, N);
        gemm_rb<256, 256, true, true, true, true, true>
            <<<G, 256, 0, stream>>>(tmpb, fct + (n * 2 + 1) * 65536, fc_b + (n * 2 + 1) * 256, x, x,
                                    xb, N);
    }
}

// Round 4
// 968.930 us; speedup vs baseline: 2.1363x; 1.4676x over previous
//
#include <hip/hip_runtime.h>
#include <hip/hip_bf16.h>

typedef __bf16 bf16_t;
typedef bf16_t bf16x8 __attribute__((ext_vector_type(8)));
typedef bf16_t bf16x4 __attribute__((ext_vector_type(4)));
typedef float f32x4 __attribute__((ext_vector_type(4)));

#define DD 256
#define MM 64
#define RR 12

__device__ __forceinline__ float gelu_tanh(float x) {
    float x3 = x * x * x;
    return 0.5f * x * (1.0f + tanhf(0.7978845608028654f * (x + 0.044715f * x3)));
}

__device__ __forceinline__ bf16x8 zero8() {
    bf16x8 z;
#pragma unroll
    for (int i = 0; i < 8; ++i) z[i] = (bf16_t)0.f;
    return z;
}

// ---------- weight prep: fp32 [K][C] -> bf16 transposed [C][K], batched over blockIdx.y ----------
__global__ void cvt_transpose_kernel(const float* __restrict__ src, bf16_t* __restrict__ dst,
                                     int K, int C) {
    int m = blockIdx.y;
    const float* s = src + (size_t)m * K * C;
    bf16_t* d = dst + (size_t)m * K * C;
    int idx = blockIdx.x * 256 + threadIdx.x;
    if (idx < K * C) {
        int k = idx / C, c = idx - k * C;
        d[c * K + k] = (bf16_t)s[idx];
    }
}

// ---------- register-B MFMA GEMM (used for Wv only) ----------
template <int K, int NCOL>
__global__ __launch_bounds__(256, 2) void gemm_rb(const bf16_t* __restrict__ A,
                                                  const bf16_t* __restrict__ Wt,
                                                  bf16_t* __restrict__ Cb, int M) {
    constexpr int NSTEP = K / 32;
    constexpr int NF = NCOL / 64;
    const int t = threadIdx.x;
    const int wave = t >> 6, lane = t & 63;
    const int l15 = lane & 15, lhi = lane >> 4;
    const int colbase = wave * (NCOL / 4);

    bf16x8 bfr[NSTEP][NF];
#pragma unroll
    for (int ks = 0; ks < NSTEP; ++ks)
#pragma unroll
        for (int nf = 0; nf < NF; ++nf)
            bfr[ks][nf] =
                *(const bf16x8*)(Wt + (size_t)(colbase + nf * 16 + l15) * K + ks * 32 + lhi * 8);

    const bf16x8 z8 = zero8();
    for (int row0 = blockIdx.x * 32; row0 < M; row0 += gridDim.x * 32) {
        const int r0 = row0 + l15, r1 = row0 + 16 + l15;
        const bool g0 = r0 < M, g1 = r1 < M;
        const bf16_t* a0p = A + (size_t)r0 * K + lhi * 8;
        const bf16_t* a1p = A + (size_t)r1 * K + lhi * 8;

        f32x4 acc[2][NF];
#pragma unroll
        for (int mf = 0; mf < 2; ++mf)
#pragma unroll
            for (int nf = 0; nf < NF; ++nf) acc[mf][nf] = (f32x4){0.f, 0.f, 0.f, 0.f};

        bf16x8 a0 = g0 ? *(const bf16x8*)a0p : z8;
        bf16x8 a1 = g1 ? *(const bf16x8*)a1p : z8;
#pragma unroll
        for (int ks = 0; ks < NSTEP; ++ks) {
            bf16x8 n0 = z8, n1 = z8;
            if (ks + 1 < NSTEP) {
                n0 = g0 ? *(const bf16x8*)(a0p + (ks + 1) * 32) : z8;
                n1 = g1 ? *(const bf16x8*)(a1p + (ks + 1) * 32) : z8;
            }
#pragma unroll
            for (int nf = 0; nf < NF; ++nf)
                acc[0][nf] = __builtin_amdgcn_mfma_f32_16x16x32_bf16(a0, bfr[ks][nf], acc[0][nf], 0, 0, 0);
#pragma unroll
            for (int nf = 0; nf < NF; ++nf)
                acc[1][nf] = __builtin_amdgcn_mfma_f32_16x16x32_bf16(a1, bfr[ks][nf], acc[1][nf], 0, 0, 0);
            a0 = n0;
            a1 = n1;
        }
#pragma unroll
        for (int mf = 0; mf < 2; ++mf)
#pragma unroll
            for (int nf = 0; nf < NF; ++nf) {
                int col = colbase + nf * 16 + l15;
#pragma unroll
                for (int r = 0; r < 4; ++r) {
                    int row = row0 + mf * 16 + lhi * 4 + r;
                    if (row < M) Cb[(size_t)row * NCOL + col] = (bf16_t)acc[mf][nf][r];
                }
            }
    }
}

// ---------- fused interaction block: x = x + agg@Wout; x = x + gelu(gelu(x@W1+b1)@W2+b2) ----------
// 512 threads = 8 waves; wave owns 32 output cols; 32-row tiles; B in VGPRs; LDS for intermediates.
__global__ __launch_bounds__(512, 2) void block_fused(
    const bf16_t* __restrict__ aggb, float* __restrict__ x, bf16_t* __restrict__ xb,
    const bf16_t* __restrict__ woutt, const bf16_t* __restrict__ fc1t,
    const bf16_t* __restrict__ fc2t, const float* __restrict__ b1, const float* __restrict__ b2,
    int M) {
    __shared__ bf16_t lds1[32][264];
    __shared__ bf16_t lds2[32][264];
    const int t = threadIdx.x, wave = t >> 6, lane = t & 63;
    const int l15 = lane & 15, lhi = lane >> 4;
    const int cb = wave * 32;

    bf16x8 bw[2][2], br1[8][2], br2[8][2];
#pragma unroll
    for (int ks = 0; ks < 2; ++ks)
#pragma unroll
        for (int nf = 0; nf < 2; ++nf)
            bw[ks][nf] = *(const bf16x8*)(woutt + (size_t)(cb + nf * 16 + l15) * 64 + ks * 32 + lhi * 8);
#pragma unroll
    for (int ks = 0; ks < 8; ++ks)
#pragma unroll
        for (int nf = 0; nf < 2; ++nf) {
            br1[ks][nf] = *(const bf16x8*)(fc1t + (size_t)(cb + nf * 16 + l15) * 256 + ks * 32 + lhi * 8);
            br2[ks][nf] = *(const bf16x8*)(fc2t + (size_t)(cb + nf * 16 + l15) * 256 + ks * 32 + lhi * 8);
        }
    float bias1[2], bias2[2];
#pragma unroll
    for (int nf = 0; nf < 2; ++nf) {
        bias1[nf] = b1[cb + nf * 16 + l15];
        bias2[nf] = b2[cb + nf * 16 + l15];
    }

    const bf16x8 z8 = zero8();
    for (int row0 = blockIdx.x * 32; row0 < M; row0 += gridDim.x * 32) {
        const int r0 = row0 + l15, r1 = row0 + 16 + l15;
        const bool g0 = r0 < M, g1 = r1 < M;

        // ---- Wout projection (K=64) ----
        f32x4 h[2][2];
#pragma unroll
        for (int mf = 0; mf < 2; ++mf)
#pragma unroll
            for (int nf = 0; nf < 2; ++nf) h[mf][nf] = (f32x4){0.f, 0.f, 0.f, 0.f};
#pragma unroll
        for (int ks = 0; ks < 2; ++ks) {
            bf16x8 a0 = g0 ? *(const bf16x8*)(aggb + (size_t)r0 * 64 + ks * 32 + lhi * 8) : z8;
            bf16x8 a1 = g1 ? *(const bf16x8*)(aggb + (size_t)r1 * 64 + ks * 32 + lhi * 8) : z8;
#pragma unroll
            for (int nf = 0; nf < 2; ++nf) {
                h[0][nf] = __builtin_amdgcn_mfma_f32_16x16x32_bf16(a0, bw[ks][nf], h[0][nf], 0, 0, 0);
                h[1][nf] = __builtin_amdgcn_mfma_f32_16x16x32_bf16(a1, bw[ks][nf], h[1][nf], 0, 0, 0);
            }
        }
        // ---- + residual x, stage fc1 input ----
#pragma unroll
        for (int mf = 0; mf < 2; ++mf)
#pragma unroll
            for (int nf = 0; nf < 2; ++nf) {
                int col = cb + nf * 16 + l15;
#pragma unroll
                for (int r = 0; r < 4; ++r) {
                    int lrow = mf * 16 + lhi * 4 + r;
                    int row = row0 + lrow;
                    float hv = h[mf][nf][r];
                    if (row < M) hv += x[(size_t)row * 256 + col];
                    h[mf][nf][r] = hv;
                    lds1[lrow][col] = (bf16_t)hv;
                }
            }
        __syncthreads();
        // ---- fc1 ----
        f32x4 acc[2][2];
#pragma unroll
        for (int mf = 0; mf < 2; ++mf)
#pragma unroll
            for (int nf = 0; nf < 2; ++nf) acc[mf][nf] = (f32x4){0.f, 0.f, 0.f, 0.f};
#pragma unroll
        for (int ks = 0; ks < 8; ++ks) {
            bf16x8 a0 = *(const bf16x8*)&lds1[l15][ks * 32 + lhi * 8];
            bf16x8 a1 = *(const bf16x8*)&lds1[16 + l15][ks * 32 + lhi * 8];
#pragma unroll
            for (int nf = 0; nf < 2; ++nf) {
                acc[0][nf] = __builtin_amdgcn_mfma_f32_16x16x32_bf16(a0, br1[ks][nf], acc[0][nf], 0, 0, 0);
                acc[1][nf] = __builtin_amdgcn_mfma_f32_16x16x32_bf16(a1, br1[ks][nf], acc[1][nf], 0, 0, 0);
            }
        }
#pragma unroll
        for (int mf = 0; mf < 2; ++mf)
#pragma unroll
            for (int nf = 0; nf < 2; ++nf) {
                int col = cb + nf * 16 + l15;
#pragma unroll
                for (int r = 0; r < 4; ++r)
                    lds2[mf * 16 + lhi * 4 + r][col] = (bf16_t)gelu_tanh(acc[mf][nf][r] + bias1[nf]);
            }
        __syncthreads();
        // ---- fc2 ----
#pragma unroll
        for (int mf = 0; mf < 2; ++mf)
#pragma unroll
            for (int nf = 0; nf < 2; ++nf) acc[mf][nf] = (f32x4){0.f, 0.f, 0.f, 0.f};
#pragma unroll
        for (int ks = 0; ks < 8; ++ks) {
            bf16x8 a0 = *(const bf16x8*)&lds2[l15][ks * 32 + lhi * 8];
            bf16x8 a1 = *(const bf16x8*)&lds2[16 + l15][ks * 32 + lhi * 8];
#pragma unroll
            for (int nf = 0; nf < 2; ++nf) {
                acc[0][nf] = __builtin_amdgcn_mfma_f32_16x16x32_bf16(a0, br2[ks][nf], acc[0][nf], 0, 0, 0);
                acc[1][nf] = __builtin_amdgcn_mfma_f32_16x16x32_bf16(a1, br2[ks][nf], acc[1][nf], 0, 0, 0);
            }
        }
        // ---- out = h + gelu(fc2 + b2) ----
#pragma unroll
        for (int mf = 0; mf < 2; ++mf)
#pragma unroll
            for (int nf = 0; nf < 2; ++nf) {
                int col = cb + nf * 16 + l15;
#pragma unroll
                for (int r = 0; r < 4; ++r) {
                    int row = row0 + mf * 16 + lhi * 4 + r;
                    if (row < M) {
                        float o = h[mf][nf][r] + gelu_tanh(acc[mf][nf][r] + bias2[nf]);
                        x[(size_t)row * 256 + col] = o;
                        xb[(size_t)row * 256 + col] = (bf16_t)o;
                    }
                }
            }
    }
}

// ---------- fused init: embed -> fc0.1 -> fc0.2 (no residual) ----------
__global__ __launch_bounds__(512, 2) void fc0_fused(
    const int* __restrict__ z, const float* __restrict__ table, const float* __restrict__ embW,
    const float* __restrict__ embb, const bf16_t* __restrict__ fc1t,
    const bf16_t* __restrict__ fc2t, const float* __restrict__ b1, const float* __restrict__ b2,
    float* __restrict__ x, bf16_t* __restrict__ xb, int M) {
    __shared__ bf16_t lds1[32][264];
    __shared__ bf16_t lds2[32][264];
    const int t = threadIdx.x, wave = t >> 6, lane = t & 63;
    const int l15 = lane & 15, lhi = lane >> 4;
    const int cb = wave * 32;
    const int erow = t >> 4, ecol0 = (t & 15) * 16;

    bf16x8 br1[8][2], br2[8][2];
#pragma unroll
    for (int ks = 0; ks < 8; ++ks)
#pragma unroll
        for (int nf = 0; nf < 2; ++nf) {
            br1[ks][nf] = *(const bf16x8*)(fc1t + (size_t)(cb + nf * 16 + l15) * 256 + ks * 32 + lhi * 8);
            br2[ks][nf] = *(const bf16x8*)(fc2t + (size_t)(cb + nf * 16 + l15) * 256 + ks * 32 + lhi * 8);
        }
    float bias1[2], bias2[2];
#pragma unroll
    for (int nf = 0; nf < 2; ++nf) {
        bias1[nf] = b1[cb + nf * 16 + l15];
        bias2[nf] = b2[cb + nf * 16 + l15];
    }

    for (int row0 = blockIdx.x * 32; row0 < M; row0 += gridDim.x * 32) {
        // ---- embed into lds1 ----
        int grow = row0 + erow;
        if (grow < M) {
            int zi = z[grow];
            float tr[5];
#pragma unroll
            for (int hh = 0; hh < 5; ++hh) tr[hh] = table[zi * 5 + hh];
#pragma unroll
            for (int c = 0; c < 16; ++c) {
                int col = ecol0 + c;
                float a = embb[col];
#pragma unroll
                for (int hh = 0; hh < 5; ++hh) a += tr[hh] * embW[hh * 256 + col];
                lds1[erow][col] = (bf16_t)a;
            }
        } else {
#pragma unroll
            for (int c = 0; c < 16; ++c) lds1[erow][ecol0 + c] = (bf16_t)0.f;
        }
        __syncthreads();
        // ---- fc0.1 ----
        f32x4 acc[2][2];
#pragma unroll
        for (int mf = 0; mf < 2; ++mf)
#pragma unroll
            for (int nf = 0; nf < 2; ++nf) acc[mf][nf] = (f32x4){0.f, 0.f, 0.f, 0.f};
#pragma unroll
        for (int ks = 0; ks < 8; ++ks) {
            bf16x8 a0 = *(const bf16x8*)&lds1[l15][ks * 32 + lhi * 8];
            bf16x8 a1 = *(const bf16x8*)&lds1[16 + l15][ks * 32 + lhi * 8];
#pragma unroll
            for (int nf = 0; nf < 2; ++nf) {
                acc[0][nf] = __builtin_amdgcn_mfma_f32_16x16x32_bf16(a0, br1[ks][nf], acc[0][nf], 0, 0, 0);
                acc[1][nf] = __builtin_amdgcn_mfma_f32_16x16x32_bf16(a1, br1[ks][nf], acc[1][nf], 0, 0, 0);
            }
        }
#pragma unroll
        for (int mf = 0; mf < 2; ++mf)
#pragma unroll
            for (int nf = 0; nf < 2; ++nf) {
                int col = cb + nf * 16 + l15;
#pragma unroll
                for (int r = 0; r < 4; ++r)
                    lds2[mf * 16 + lhi * 4 + r][col] = (bf16_t)gelu_tanh(acc[mf][nf][r] + bias1[nf]);
            }
        __syncthreads();
        // ---- fc0.2 ----
#pragma unroll
        for (int mf = 0; mf < 2; ++mf)
#pragma unroll
            for (int nf = 0; nf < 2; ++nf) acc[mf][nf] = (f32x4){0.f, 0.f, 0.f, 0.f};
#pragma unroll
        for (int ks = 0; ks < 8; ++ks) {
            bf16x8 a0 = *(const bf16x8*)&lds2[l15][ks * 32 + lhi * 8];
            bf16x8 a1 = *(const bf16x8*)&lds2[16 + l15][ks * 32 + lhi * 8];
#pragma unroll
            for (int nf = 0; nf < 2; ++nf) {
                acc[0][nf] = __builtin_amdgcn_mfma_f32_16x16x32_bf16(a0, br2[ks][nf], acc[0][nf], 0, 0, 0);
                acc[1][nf] = __builtin_amdgcn_mfma_f32_16x16x32_bf16(a1, br2[ks][nf], acc[1][nf], 0, 0, 0);
            }
        }
#pragma unroll
        for (int mf = 0; mf < 2; ++mf)
#pragma unroll
            for (int nf = 0; nf < 2; ++nf) {
                int col = cb + nf * 16 + l15;
#pragma unroll
                for (int r = 0; r < 4; ++r) {
                    int row = row0 + mf * 16 + lhi * 4 + r;
                    if (row < M) {
                        float o = gelu_tanh(acc[mf][nf][r] + bias2[nf]);
                        x[(size_t)row * 256 + col] = o;
                        xb[(size_t)row * 256 + col] = (bf16_t)o;
                    }
                }
            }
    }
}

// ---------- CSR build ----------
__global__ void count_kernel(const int* __restrict__ ei, int* __restrict__ deg, int E) {
    int e = blockIdx.x * 256 + threadIdx.x;
    if (e < E) atomicAdd(&deg[ei[e]], 1);
}

__global__ void scan_local(const int* __restrict__ deg, int* __restrict__ rs,
                           int* __restrict__ bsum, int N) {
    __shared__ int sd[1024];
    int t = threadIdx.x, i = blockIdx.x * 1024 + t;
    int val = (i < N) ? deg[i] : 0;
    sd[t] = val;
    __syncthreads();
    for (int off = 1; off < 1024; off <<= 1) {
        int tv = (t >= off) ? sd[t - off] : 0;
        __syncthreads();
        sd[t] += tv;
        __syncthreads();
    }
    if (i < N) rs[i] = sd[t] - val;
    if (t == 1023) bsum[blockIdx.x] = sd[1023];
}

__global__ void scan_bsums(int* __restrict__ bsum, int nb) {
    if (threadIdx.x == 0) {
        int run = 0;
        for (int b = 0; b < nb; ++b) {
            int v = bsum[b];
            bsum[b] = run;
            run += v;
        }
        bsum[nb] = run;
    }
}

__global__ void scan_add(int* __restrict__ rs, const int* __restrict__ bsum, int N) {
    int i = blockIdx.x * 1024 + threadIdx.x;
    if (i < N) rs[i] += bsum[blockIdx.x];
    if (i == 0) rs[N] = bsum[gridDim.x];
}

__global__ void fill_kernel(const int* __restrict__ ei, const int* __restrict__ row_start,
                            int* __restrict__ cursor, int* __restrict__ csr_eid,
                            int* __restrict__ csr_j, int E) {
    int e = blockIdx.x * 256 + threadIdx.x;
    if (e < E) {
        int i = ei[e];
        int p = atomicAdd(&cursor[i], 1);
        int o = row_start[i] + p;
        csr_eid[o] = e;
        csr_j[o] = ei[E + e];
    }
}

// ---------- rbf in CSR order (bf16, rows padded to 16 elems / 32B) ----------
__global__ void rbf_csr_kernel(const int* __restrict__ csr_eid, const int* __restrict__ ei,
                               const float* __restrict__ pos, const float* __restrict__ freqs,
                               bf16_t* __restrict__ rbf_csr, int E) {
    int idx = blockIdx.x * 256 + threadIdx.x;
    if (idx >= E) return;
    int e = csr_eid[idx];
    int i = ei[e], j = ei[E + e];
    float dx = pos[i * 3 + 0] - pos[j * 3 + 0];
    float dy = pos[i * 3 + 1] - pos[j * 3 + 1];
    float dz = pos[i * 3 + 2] - pos[j * 3 + 2];
    float dist = sqrtf(dx * dx + dy * dy + dz * dz + 1e-12f);
    float x = dist * 0.2f;
    float x4 = (x * x) * (x * x);
    float env = 1.0f / x + x4 * (-21.0f + x * (35.0f - 15.0f * x));
    bf16x8 lo;
    bf16x4 hi;
#pragma unroll
    for (int r = 0; r < 8; ++r) lo[r] = (bf16_t)(env * sinf(freqs[r] * x));
#pragma unroll
    for (int r = 0; r < 4; ++r) hi[r] = (bf16_t)(env * sinf(freqs[8 + r] * x));
    bf16_t* dst = rbf_csr + (size_t)idx * 16;
    *(bf16x8*)dst = lo;
    *(bf16x4*)(dst + 8) = hi;
}

// ---------- message gather ----------
__device__ __forceinline__ float gdot(const bf16_t* __restrict__ rb, const float* __restrict__ wr) {
    bf16x8 a = *(const bf16x8*)rb;
    bf16x4 b = *(const bf16x4*)(rb + 8);
    float g = 0.f;
#pragma unroll
    for (int r = 0; r < 8; ++r) g += (float)a[r] * wr[r];
#pragma unroll
    for (int r = 0; r < 4; ++r) g += (float)b[r] * wr[8 + r];
    return g;
}

__global__ __launch_bounds__(256) void msg_kernel(const int* __restrict__ row_start,
                                                  const int* __restrict__ csr_j,
                                                  const bf16_t* __restrict__ rbf_csr,
                                                  const bf16_t* __restrict__ v,
                                                  const float* __restrict__ Wrbf,
                                                  bf16_t* __restrict__ agg, int N) {
    int wave = threadIdx.x >> 6, lane = threadIdx.x & 63;
    int nd = blockIdx.x * 4 + wave;
    if (nd >= N) return;
    float wr[12];
#pragma unroll
    for (int r = 0; r < 12; ++r) wr[r] = Wrbf[r * 64 + lane];
    int s = row_start[nd], e = row_start[nd + 1];
    float acc = 0.f;
    int idx = s;
    for (; idx + 4 <= e; idx += 4) {
        float vv[4], gg[4];
#pragma unroll
        for (int u = 0; u < 4; ++u) {
            int j = csr_j[idx + u];
            vv[u] = (float)v[(size_t)j * 64 + lane];
            gg[u] = gdot(rbf_csr + (size_t)(idx + u) * 16, wr);
        }
#pragma unroll
        for (int u = 0; u < 4; ++u) acc += vv[u] * gg[u];
    }
    for (; idx < e; ++idx) {
        int j = csr_j[idx];
        acc += (float)v[(size_t)j * 64 + lane] * gdot(rbf_csr + (size_t)idx * 16, wr);
    }
    agg[(size_t)nd * 64 + lane] = (bf16_t)acc;
}

extern "C" void kernel_launch(void* const* d_in, const int* in_sizes, int n_in, void* d_out,
                              int out_size, void* d_ws, size_t ws_size, hipStream_t stream) {
    const int* z = (const int*)d_in[0];
    const float* pos = (const float*)d_in[1];
    const int* ei = (const int*)d_in[4];
    const float* emb_table = (const float*)d_in[5];
    const float* emb_W = (const float*)d_in[6];
    const float* emb_b = (const float*)d_in[7];
    const float* freqs = (const float*)d_in[8];
    const float* fc0_W = (const float*)d_in[9];
    const float* fc0_b = (const float*)d_in[10];
    const float* conv_Wv = (const float*)d_in[11];
    const float* conv_Wrbf = (const float*)d_in[12];
    const float* conv_Wout = (const float*)d_in[13];
    const float* fc_W = (const float*)d_in[14];
    const float* fc_b = (const float*)d_in[15];
    float* x = (float*)d_out;

    const int N = in_sizes[0];
    const int E = in_sizes[4] / 2;

    // ---- workspace carve ----
    char* wsp = (char*)d_ws;
    auto alloc = [&](size_t bytes) {
        void* p = (void*)wsp;
        wsp += (bytes + 255) & ~(size_t)255;
        return p;
    };
    bf16_t* xb = (bf16_t*)alloc((size_t)N * DD * 2);
    bf16_t* vb = (bf16_t*)alloc((size_t)N * MM * 2);
    bf16_t* aggb = (bf16_t*)alloc((size_t)N * MM * 2);
    bf16_t* rbf_csr = (bf16_t*)alloc((size_t)E * 16 * 2);
    int* deg = (int*)alloc((size_t)N * 4);
    int* cursor = (int*)alloc((size_t)N * 4);
    int* row_start = (int*)alloc((size_t)(N + 1) * 4);
    int* bsum = (int*)alloc((size_t)256 * 4);
    int* csr_eid = (int*)alloc((size_t)E * 4);
    int* csr_j = (int*)alloc((size_t)E * 4);
    bf16_t* wbf = (bf16_t*)alloc((size_t)786432 * 2);
    bf16_t* fc0t = wbf;              // 2 x [256][256]
    bf16_t* fct = wbf + 2 * 65536;   // 8 x [256][256]
    bf16_t* wvt = wbf + 10 * 65536;  // 4 x [64][256]
    bf16_t* wott = wvt + 4 * 16384;  // 4 x [256][64]

    // ---- weight prep ----
    cvt_transpose_kernel<<<dim3(256, 2), 256, 0, stream>>>(fc0_W, fc0t, 256, 256);
    cvt_transpose_kernel<<<dim3(256, 8), 256, 0, stream>>>(fc_W, fct, 256, 256);
    cvt_transpose_kernel<<<dim3(64, 4), 256, 0, stream>>>(conv_Wv, wvt, 256, 64);
    cvt_transpose_kernel<<<dim3(64, 4), 256, 0, stream>>>(conv_Wout, wott, 64, 256);

    // ---- CSR by destination, rbf in CSR order ----
    hipMemsetAsync(deg, 0, (size_t)N * 4, stream);
    hipMemsetAsync(cursor, 0, (size_t)N * 4, stream);
    count_kernel<<<(E + 255) / 256, 256, 0, stream>>>(ei, deg, E);
    const int nb = (N + 1023) / 1024;
    scan_local<<<nb, 1024, 0, stream>>>(deg, row_start, bsum, N);
    scan_bsums<<<1, 64, 0, stream>>>(bsum, nb);
    scan_add<<<nb, 1024, 0, stream>>>(row_start, bsum, N);
    fill_kernel<<<(E + 255) / 256, 256, 0, stream>>>(ei, row_start, cursor, csr_eid, csr_j, E);
    rbf_csr_kernel<<<(E + 255) / 256, 256, 0, stream>>>(csr_eid, ei, pos, freqs, rbf_csr, E);

    // ---- init: embed + fc0 fused ----
    const int GF = 512;
    fc0_fused<<<GF, 512, 0, stream>>>(z, emb_table, emb_W, emb_b, fc0t, fc0t + 65536, fc0_b,
                                      fc0_b + 256, x, xb, N);

    // ---- interaction blocks ----
    for (int n = 0; n < 4; ++n) {
        gemm_rb<256, 64><<<512, 256, 0, stream>>>(xb, wvt + n * 16384, vb, N);
        msg_kernel<<<(N + 3) / 4, 256, 0, stream>>>(row_start, csr_j, rbf_csr, vb,
                                                    conv_Wrbf + n * RR * MM, aggb, N);
        block_fused<<<GF, 512, 0, stream>>>(aggb, x, xb, wott + n * 16384, fct + (n * 2) * 65536,
                                            fct + (n * 2 + 1) * 65536, fc_b + n * 2 * 256,
                                            fc_b + (n * 2 + 1) * 256, N);
    }
}